// Round 11
// baseline (172.630 us; speedup 1.0000x reference)
//
#include <hip/hip_runtime.h>
#include <math.h>

#define BATCH 8192
#define L 100
#define EMB 16
#define NCH 384  // 4 fields * 6 pools * 16 emb channels
#define NG  512  // sample-groups (BATCH/16)
#define N_MOVIE 132000
#define N_TAG   41000

// ---------------- workspace layout (floats unless noted) ----------------
// pooled : float [4][BATCH][6][16]        = 12,582,912 B
// psum   : float [384][512]; psq : float [384][512]
// coefA/coefB : float [384]
// pk_movie : 132000 x 64 B packed records; pk_tag : 41000 x 64 B
//   record = [16 x bf16 row (32B) | att fp32 (4B) | row-l2 fp32 (4B) | pad]
#define POOLED_FLOATS (4 * BATCH * 96)
#define PART_FLOATS   (NCH * NG)
#define WS_HDR_FLOATS (POOLED_FLOATS + 2 * PART_FLOATS + 2 * NCH)

__device__ __forceinline__ unsigned bf16rne(float x) {
    unsigned u = __float_as_uint(x);
    return (u + 0x7fffu + ((u >> 16) & 1u)) >> 16;
}
__device__ __forceinline__ unsigned pack2(float a, float b) {
    return bf16rne(a) | (bf16rne(b) << 16);
}

// pack: one thread per table id. Row -> bf16 (RNE); att and EXACT fp32 l2
// (from the fp32 table, so argmax/argmin ranking matches the reference —
// bf16-rounded l2 would flip the top-2 in ~10% of samples) ride in the same
// 64 B line. Halves pool's scattered-line count: 2 lines/element -> 1.
__global__ __launch_bounds__(256) void pack_kernel(
    const float* __restrict__ emb_movie, const float* __restrict__ att_movie,
    const float* __restrict__ emb_tag,   const float* __restrict__ att_tag,
    uint4* __restrict__ pk_movie, uint4* __restrict__ pk_tag)
{
    int i = blockIdx.x * 256 + threadIdx.x;
    const float* src; float a; uint4* dst;
    if (i < N_MOVIE) {
        src = emb_movie + (size_t)i * 16; a = att_movie[i];
        dst = pk_movie + (size_t)i * 4;
    } else {
        i -= N_MOVIE;
        if (i >= N_TAG) return;
        src = emb_tag + (size_t)i * 16; a = att_tag[i];
        dst = pk_tag + (size_t)i * 4;
    }
    const float4* s4 = (const float4*)src;
    float4 r0 = s4[0], r1 = s4[1], r2 = s4[2], r3 = s4[3];
    float l2 = ((r0.x*r0.x + r0.y*r0.y) + (r0.z*r0.z + r0.w*r0.w))
             + ((r1.x*r1.x + r1.y*r1.y) + (r1.z*r1.z + r1.w*r1.w))
             + ((r2.x*r2.x + r2.y*r2.y) + (r2.z*r2.z + r2.w*r2.w))
             + ((r3.x*r3.x + r3.y*r3.y) + (r3.z*r3.z + r3.w*r3.w));
    uint4 q0, q1, q2;
    q0.x = pack2(r0.x, r0.y); q0.y = pack2(r0.z, r0.w);
    q0.z = pack2(r1.x, r1.y); q0.w = pack2(r1.z, r1.w);
    q1.x = pack2(r2.x, r2.y); q1.y = pack2(r2.z, r2.w);
    q1.z = pack2(r3.x, r3.y); q1.w = pack2(r3.z, r3.w);
    q2.x = __float_as_uint(a); q2.y = __float_as_uint(l2);
    q2.z = 0u; q2.w = 0u;
    dst[0] = q0; dst[1] = q1; dst[2] = q2;   // pad (dst[3]) never read
}

// pool: grid 2048, block 256 = 16 samples x 16 lanes (4 l-phases x 4 chunks).
// f = bx & 3 interleaves fields in dispatch order. ids staged in LDS (R10).
// Movie/tag: ONE scattered 64B record line per element (packed table); the
// 4 chunk-lanes of a phase fetch the 4 uint4 of the record and redistribute
// via broadcast shfls (no serial shfl_xor reduce in the loop — l2 arrives
// precomputed). Depth-1 software pipeline. Genre: gtab/gexp/ids in LDS.
// Stats: per-block float partials (no atomics); coef reduces in double.
// Padded tail (l >= ln): contributes 0 to s/ssq/att, exp(0)*(L-ln) added to
// the softmax denom analytically, never wins argmax (l2=0, strict >) or
// argmin (maps to 9999, first real l wins via strict <). First-index
// semantics preserved across phases by carrying l, tie -> smaller l.
__global__ __launch_bounds__(256) void pool_kernel(
    const int* __restrict__ ids_ug, const int* __restrict__ ids_urb,
    const int* __restrict__ ids_mg, const int* __restrict__ ids_mt,
    const int* __restrict__ len_ug, const int* __restrict__ len_urb,
    const int* __restrict__ len_mg, const int* __restrict__ len_mt,
    const uint4* __restrict__ pk_movie, const uint4* __restrict__ pk_tag,
    const float* __restrict__ emb_genre, const float* __restrict__ att_genre,
    float* __restrict__ pooled, float* __restrict__ psum, float* __restrict__ psq)
{
    const int bx  = blockIdx.x;
    const int f   = bx & 3;          // field, interleaved in dispatch order
    const int g   = bx >> 2;         // sample group (0..511)
    const int tid = threadIdx.x;
    const int sub = tid >> 4;        // sample within block (0..15)
    const int e   = tid & 15;        // lane within sample
    const int j   = e >> 2;          // l-phase
    const int c   = e & 3;           // chunk / record-quarter
    const int b   = g * 16 + sub;
    const int qb  = (tid & 63) & ~3; // quad base lane within wave

    const int* ids; const int* lens; const uint4* pk;
    switch (f) {
        case 0: ids = ids_ug;  lens = len_ug;  pk = 0;         break;
        case 1: ids = ids_urb; lens = len_urb; pk = pk_movie;  break;
        case 2: ids = ids_mg;  lens = len_mg;  pk = 0;         break;
        default:ids = ids_mt;  lens = len_mt;  pk = pk_tag;    break;
    }
    const int ln = lens[b];

    __shared__ float tile[16][100];  // stats tile (stride 100, odd pad)
    __shared__ int   sids[16 * 100]; // block's id rows (coalesced staging)
    __shared__ float gtab[480];      // genre table (30 rows x 16)
    __shared__ float gexp[32];       // exp(att_genre)

    {   // coalesced int4 staging of all 16 id rows (1600 ints = 400 int4)
        const int4* idsrc = (const int4*)(ids + (size_t)g * (16 * L));
        ((int4*)sids)[tid] = idsrc[tid];
        if (tid < 144) ((int4*)sids)[256 + tid] = idsrc[256 + tid];
    }
    const bool genre = (f == 0) | (f == 2);
    if (genre) {                     // block-uniform branch
        for (int i = tid; i < 480; i += 256) gtab[i] = emb_genre[i];
        if (tid < 30) gexp[tid] = __expf(att_genre[tid]);
    }
    __syncthreads();
    const int* idrow = &sids[sub * 100];

    float4 s   = make_float4(0.f, 0.f, 0.f, 0.f);
    float4 ssq = s, att = s, mxv = s, mnv = s;
    float expsum = 0.f;
    float bestmx = -1e30f; int lx = 0x7fffffff;
    float bestmn =  1e30f; int lm = 0x7fffffff;

    // shared accumulate tail given v (this lane's 4 dims), per-row l2, exp(aw)
    auto ACCV = [&](const float4 v, const float l2v, const float ew, const int l) {
        s.x += v.x; s.y += v.y; s.z += v.z; s.w += v.w;
        ssq.x += v.x * v.x; ssq.y += v.y * v.y;
        ssq.z += v.z * v.z; ssq.w += v.w * v.w;
        if (l2v > bestmx) { bestmx = l2v; lx = l; mxv = v; }   // first-max
        float l2m = (l2v == 0.0f) ? 9999.0f : l2v;
        if (l2m < bestmn) { bestmn = l2m; lm = l; mnv = v; }   // first-min
        expsum += ew;
        att.x += v.x * ew; att.y += v.y * ew; att.z += v.z * ew; att.w += v.w * ew;
    };

    if (!genre) {
        // unpack a record quarter held per-lane into (v, l2, aw) and ACC
        auto ACCP = [&](const uint4 q, const int l) {
            float aw  = __uint_as_float(__shfl((int)q.x, qb + 2, 64));
            float l2v = __uint_as_float(__shfl((int)q.y, qb + 2, 64));
            const int rs = qb + (c >> 1);
            unsigned wa = (unsigned)__shfl((int)q.x, rs, 64);
            unsigned wb = (unsigned)__shfl((int)q.y, rs, 64);
            unsigned wc = (unsigned)__shfl((int)q.z, rs, 64);
            unsigned wd = (unsigned)__shfl((int)q.w, rs, 64);
            const unsigned u0 = (c & 1) ? wc : wa;
            const unsigned u1 = (c & 1) ? wd : wb;
            float4 v;
            v.x = __uint_as_float(u0 << 16);
            v.y = __uint_as_float(u0 & 0xffff0000u);
            v.z = __uint_as_float(u1 << 16);
            v.w = __uint_as_float(u1 & 0xffff0000u);
            ACCV(v, l2v, __expf(aw), l);
        };
        // depth-1 pipeline: next record line in flight during ACC
        int l = j;
        if (l < ln) {
            uint4 q0 = pk[(size_t)idrow[l] * 4 + c];
            while (l + 4 < ln) {
                uint4 q1 = pk[(size_t)idrow[l + 4] * 4 + c];
                ACCP(q0, l);
                q0 = q1; l += 4;
            }
            ACCP(q0, l);
        }
    } else {
        // fully LDS-resident loop; l2 via quad reduce (exact fp32)
        for (int l = j; l < ln; l += 4) {
            const int id = idrow[l];
            float4 v = *(const float4*)&gtab[id * 16 + c * 4];
            float pl2 = (v.x * v.x + v.y * v.y) + (v.z * v.z + v.w * v.w);
            float l2v = pl2 + __shfl_xor(pl2, 1);
            l2v += __shfl_xor(l2v, 2);
            ACCV(v, l2v, gexp[id], l);
        }
    }

    // cross-phase merges (masks 4, 8 flip j-bits; stay within 16-lane group)
    #pragma unroll
    for (int m = 4; m <= 8; m <<= 1) {
        float obx = __shfl_xor(bestmx, m);
        int   olx = __shfl_xor(lx, m);
        float ax = __shfl_xor(mxv.x, m), ay = __shfl_xor(mxv.y, m);
        float az = __shfl_xor(mxv.z, m), aw2 = __shfl_xor(mxv.w, m);
        if (obx > bestmx || (obx == bestmx && olx < lx)) {
            bestmx = obx; lx = olx; mxv = make_float4(ax, ay, az, aw2);
        }
        float obn = __shfl_xor(bestmn, m);
        int   olm = __shfl_xor(lm, m);
        float bx2 = __shfl_xor(mnv.x, m), by = __shfl_xor(mnv.y, m);
        float bz  = __shfl_xor(mnv.z, m), bw = __shfl_xor(mnv.w, m);
        if (obn < bestmn || (obn == bestmn && olm < lm)) {
            bestmn = obn; lm = olm; mnv = make_float4(bx2, by, bz, bw);
        }
        s.x += __shfl_xor(s.x, m); s.y += __shfl_xor(s.y, m);
        s.z += __shfl_xor(s.z, m); s.w += __shfl_xor(s.w, m);
        ssq.x += __shfl_xor(ssq.x, m); ssq.y += __shfl_xor(ssq.y, m);
        ssq.z += __shfl_xor(ssq.z, m); ssq.w += __shfl_xor(ssq.w, m);
        att.x += __shfl_xor(att.x, m); att.y += __shfl_xor(att.y, m);
        att.z += __shfl_xor(att.z, m); att.w += __shfl_xor(att.w, m);
        expsum += __shfl_xor(expsum, m);
    }
    expsum += (float)(L - ln);   // analytic padded-tail exp(0) contributions

    float4 mean;
    mean.x = s.x * (1.0f / L); mean.y = s.y * (1.0f / L);
    mean.z = s.z * (1.0f / L); mean.w = s.w * (1.0f / L);
    float4 ko;
    ko.x = 0.5f * (s.x * s.x - ssq.x); ko.y = 0.5f * (s.y * s.y - ssq.y);
    ko.z = 0.5f * (s.z * s.z - ssq.z); ko.w = 0.5f * (s.w * s.w - ssq.w);
    float pk2 = (ko.x * ko.x + ko.y * ko.y) + (ko.z * ko.z + ko.w * ko.w);
    float kn2 = pk2 + __shfl_xor(pk2, 1);
    kn2 += __shfl_xor(kn2, 2);
    float rn = 1.0f / fmaxf(sqrtf(kn2), 1e-12f);
    ko.x *= rn; ko.y *= rn; ko.z *= rn; ko.w *= rn;
    float ie = 1.0f / expsum;
    att.x *= ie; att.y *= ie; att.z *= ie; att.w *= ie;

    float4 pv[6] = { s, mean, mxv, mnv, ko, att };

    float4* prow = (float4*)(pooled + ((size_t)(f * BATCH + b)) * 96);
    if (j == 0) {                     // e < 4, c == e
        #pragma unroll
        for (int p = 0; p < 6; ++p) {
            prow[p * 4 + c] = pv[p];
            *(float4*)&tile[sub][p * 16 + c * 4] = pv[p];
        }
    }
    __syncthreads();
    // block-level partial stats -> plain stores (no atomics)
    if (tid < 96) {
        float sm = 0.f, sq = 0.f;
        #pragma unroll
        for (int s2 = 0; s2 < 16; ++s2) {
            float x = tile[s2][tid];
            sm += x;
            sq += x * x;
        }
        psum[(size_t)(f * 96 + tid) * NG + g] = sm;
        psq [(size_t)(f * 96 + tid) * NG + g] = sq;
    }
}

// coef: grid 12 x 256. Block covers 32 channels; 8 threads per channel
// reduce its 512 partials (coalesced float4 strips) in DOUBLE, then fold
// BN affine + softmax(alpha) weight into per-channel A,B.
__global__ __launch_bounds__(256) void coef_kernel(
    const float* __restrict__ psum, const float* __restrict__ psq,
    const float* __restrict__ gamma, const float* __restrict__ beta,
    const float* __restrict__ alpha,
    float* __restrict__ coefA, float* __restrict__ coefB)
{
    const int tid   = threadIdx.x;
    const int chl   = tid >> 3;              // local channel 0..31
    const int strip = tid & 7;               // 0..7
    const int ch    = blockIdx.x * 32 + chl; // 0..383
    const float4* ps = (const float4*)(psum + (size_t)ch * NG + strip * 64);
    const float4* pq = (const float4*)(psq  + (size_t)ch * NG + strip * 64);
    double dsm = 0.0, dsq = 0.0;
    #pragma unroll
    for (int i = 0; i < 16; ++i) {
        float4 a = ps[i];
        dsm += ((double)a.x + (double)a.y) + ((double)a.z + (double)a.w);
        float4 bq = pq[i];
        dsq += ((double)bq.x + (double)bq.y) + ((double)bq.z + (double)bq.w);
    }
    #pragma unroll
    for (int m = 1; m <= 4; m <<= 1) {
        dsm += __shfl_xor(dsm, m);
        dsq += __shfl_xor(dsq, m);
    }
    if (strip == 0) {
        const int f = ch / 96;
        const int p = (ch % 96) >> 4;
        double mu  = dsm * (1.0 / BATCH);
        double var = dsq * (1.0 / BATCH) - mu * mu;
        float inv = (float)(1.0 / sqrt(var + 1e-5));
        float gm = gamma[ch];
        float bb = beta[ch];
        float amax = -1e30f;
        for (int q = 0; q < 6; ++q) amax = fmaxf(amax, alpha[f * 6 + q]);
        float wsum = 0.f;
        for (int q = 0; q < 6; ++q) wsum += __expf(alpha[f * 6 + q] - amax);
        float wp = __expf(alpha[f * 6 + p] - amax) / wsum;
        coefA[ch] = wp * gm * inv;
        coefB[ch] = wp * (bb - gm * (float)mu * inv);
    }
}

#define SPB 16
__global__ __launch_bounds__(256) void final_kernel(
    const int* __restrict__ uid, const int* __restrict__ mid, const int* __restrict__ yr,
    const float* __restrict__ emb_user, const float* __restrict__ emb_movie,
    const float* __restrict__ emb_year,
    const float* __restrict__ pooled,
    const float* __restrict__ coefA, const float* __restrict__ coefB,
    const float* __restrict__ W1, const float* __restrict__ b1,
    const float* __restrict__ W2, const float* __restrict__ b2,
    const float* __restrict__ W3, const float* __restrict__ b3,
    float* __restrict__ out)
{
    __shared__ float sW1[112 * 64];   // [k][j], j contiguous
    __shared__ float sW2[64 * 32];
    __shared__ float sW3[32];
    __shared__ float sb1[64];
    __shared__ float sb2[32];
    __shared__ float xt[SPB][112];
    __shared__ float h1t[SPB][64];

    const int tid = threadIdx.x;
    for (int i = tid; i < 112 * 16; i += 256)
        ((float4*)sW1)[i] = ((const float4*)W1)[i];
    for (int i = tid; i < 64 * 8; i += 256)
        ((float4*)sW2)[i] = ((const float4*)W2)[i];
    if (tid < 32) sW3[tid] = W3[tid];
    if (tid < 64) sb1[tid] = b1[tid];
    if (tid < 32) sb2[tid] = b2[tid];

    const int sub = tid >> 4;
    const int e   = tid & 15;
    const int b   = blockIdx.x * SPB + sub;

    xt[sub][e]      = emb_user [(size_t)uid[b] * EMB + e];
    xt[sub][16 + e] = emb_movie[(size_t)mid[b] * EMB + e];
    xt[sub][32 + e] = emb_year [(size_t)yr[b]  * EMB + e];

    #pragma unroll
    for (int f = 0; f < 4; ++f) {
        const float* pr = pooled + ((size_t)(f * BATCH + b)) * 96;
        float acc = 0.f;
        #pragma unroll
        for (int p = 0; p < 6; ++p) {
            int c = f * 96 + p * 16 + e;
            acc += coefA[c] * pr[p * 16 + e] + coefB[c];
        }
        xt[sub][48 + f * 16 + e] = acc;
    }
    __syncthreads();

    // h1 = relu(x @ W1 + b1): lane e computes j = 4e..4e+3 via float4
    float4 h1 = ((float4*)sb1)[e];
    for (int k = 0; k < 112; ++k) {
        float xk = xt[sub][k];
        float4 w = ((float4*)sW1)[k * 16 + e];
        h1.x += xk * w.x; h1.y += xk * w.y; h1.z += xk * w.z; h1.w += xk * w.w;
    }
    float4 h1r;
    h1r.x = fmaxf(h1.x, 0.f); h1r.y = fmaxf(h1.y, 0.f);
    h1r.z = fmaxf(h1.z, 0.f); h1r.w = fmaxf(h1.w, 0.f);
    *(float4*)&h1t[sub][e * 4] = h1r;
    __syncthreads();

    // h2 = relu(h1 @ W2 + b2): lane e computes j = 2e, 2e+1 via float2
    float2 h2 = ((float2*)sb2)[e];
    for (int k = 0; k < 64; ++k) {
        float hk = h1t[sub][k];
        float2 w = ((float2*)sW2)[k * 16 + e];
        h2.x += hk * w.x; h2.y += hk * w.y;
    }
    float part = fmaxf(h2.x, 0.f) * sW3[2 * e] + fmaxf(h2.y, 0.f) * sW3[2 * e + 1];
    part += __shfl_xor(part, 1);
    part += __shfl_xor(part, 2);
    part += __shfl_xor(part, 4);
    part += __shfl_xor(part, 8);
    if (e == 0) {
        float t = part + b3[0];
        out[b] = 1.f / (1.f + __expf(-t));
    }
}

extern "C" void kernel_launch(void* const* d_in, const int* in_sizes, int n_in,
                              void* d_out, int out_size, void* d_ws, size_t ws_size,
                              hipStream_t stream) {
    const int* uid     = (const int*)d_in[0];
    const int* mid     = (const int*)d_in[1];
    const int* yr      = (const int*)d_in[2];
    const int* ids_ug  = (const int*)d_in[3];
    const int* ids_urb = (const int*)d_in[4];
    const int* ids_mg  = (const int*)d_in[5];
    const int* ids_mt  = (const int*)d_in[6];
    const int* len_ug  = (const int*)d_in[7];
    const int* len_urb = (const int*)d_in[8];
    const int* len_mg  = (const int*)d_in[9];
    const int* len_mt  = (const int*)d_in[10];
    const float* emb_user  = (const float*)d_in[11];
    const float* emb_movie = (const float*)d_in[12];
    const float* emb_tag   = (const float*)d_in[13];
    const float* emb_genre = (const float*)d_in[14];
    const float* emb_year  = (const float*)d_in[15];
    const float* att_movie = (const float*)d_in[16];
    const float* att_tag   = (const float*)d_in[17];
    const float* att_genre = (const float*)d_in[18];
    const float* bn_gamma  = (const float*)d_in[19];
    const float* bn_beta   = (const float*)d_in[20];
    const float* alpha     = (const float*)d_in[21];
    const float* W1 = (const float*)d_in[22];
    const float* b1 = (const float*)d_in[23];
    const float* W2 = (const float*)d_in[24];
    const float* b2 = (const float*)d_in[25];
    const float* W3 = (const float*)d_in[26];
    const float* b3 = (const float*)d_in[27];
    float* out = (float*)d_out;

    float* pooled = (float*)d_ws;
    float* psum   = pooled + POOLED_FLOATS;
    float* psq    = psum + PART_FLOATS;
    float* coefA  = psq + PART_FLOATS;
    float* coefB  = coefA + NCH;
    uint4* pk_movie = (uint4*)((char*)d_ws + (size_t)WS_HDR_FLOATS * 4);
    uint4* pk_tag   = pk_movie + (size_t)N_MOVIE * 4;

    pack_kernel<<<(N_MOVIE + N_TAG + 255) / 256, 256, 0, stream>>>(
        emb_movie, att_movie, emb_tag, att_tag, pk_movie, pk_tag);
    pool_kernel<<<4 * NG, 256, 0, stream>>>(
        ids_ug, ids_urb, ids_mg, ids_mt,
        len_ug, len_urb, len_mg, len_mt,
        pk_movie, pk_tag, emb_genre, att_genre,
        pooled, psum, psq);
    coef_kernel<<<12, 256, 0, stream>>>(psum, psq, bn_gamma, bn_beta, alpha,
                                        coefA, coefB);
    final_kernel<<<BATCH / SPB, 256, 0, stream>>>(
        uid, mid, yr, emb_user, emb_movie, emb_year,
        pooled, coefA, coefB, W1, b1, W2, b2, W3, b3, out);
}

// Round 12
// 170.535 us; speedup vs baseline: 1.0123x; 1.0123x over previous
//
#include <hip/hip_runtime.h>
#include <math.h>

#define BATCH 8192
#define L 100
#define EMB 16
#define NCH 384  // 4 fields * 6 pools * 16 emb channels
#define NG  512  // sample-groups (BATCH/16)
#define N_MOVIE 132000
#define N_TAG   41000

// ---------------- workspace layout (floats unless noted) ----------------
// pooled : float [4][BATCH][6][16]        = 12,582,912 B
// psum   : float [384][512]; psq : float [384][512]
// coefA/coefB : float [384]
// pk_movie : 132000 x 64 B packed records; pk_tag : 41000 x 64 B
//   record = 4 SELF-CONTAINED 16B quarters; quarter c =
//   [bf16 d[4c],d[4c+1] | bf16 d[4c+2],d[4c+3] | att fp32 | l2 fp32]
//   (att/l2 replicated x4 so the consuming lane needs NO cross-lane shfls —
//   R11's quartered layout halved lines but added 6 dependent shfls/element
//   which cancelled the gain.)
#define POOLED_FLOATS (4 * BATCH * 96)
#define PART_FLOATS   (NCH * NG)
#define WS_HDR_FLOATS (POOLED_FLOATS + 2 * PART_FLOATS + 2 * NCH)

__device__ __forceinline__ unsigned bf16rne(float x) {
    unsigned u = __float_as_uint(x);
    return (u + 0x7fffu + ((u >> 16) & 1u)) >> 16;
}
__device__ __forceinline__ unsigned pack2(float a, float b) {
    return bf16rne(a) | (bf16rne(b) << 16);
}

// pack: one thread per table id. Rows -> bf16 (RNE); att and EXACT fp32 l2
// (computed from the fp32 table so argmax/argmin ranking matches reference)
// replicated into each 16B quarter.
__global__ __launch_bounds__(256) void pack_kernel(
    const float* __restrict__ emb_movie, const float* __restrict__ att_movie,
    const float* __restrict__ emb_tag,   const float* __restrict__ att_tag,
    uint4* __restrict__ pk_movie, uint4* __restrict__ pk_tag)
{
    int i = blockIdx.x * 256 + threadIdx.x;
    const float* src; float a; uint4* dst;
    if (i < N_MOVIE) {
        src = emb_movie + (size_t)i * 16; a = att_movie[i];
        dst = pk_movie + (size_t)i * 4;
    } else {
        i -= N_MOVIE;
        if (i >= N_TAG) return;
        src = emb_tag + (size_t)i * 16; a = att_tag[i];
        dst = pk_tag + (size_t)i * 4;
    }
    const float4* s4 = (const float4*)src;
    float4 r[4];
    r[0] = s4[0]; r[1] = s4[1]; r[2] = s4[2]; r[3] = s4[3];
    float l2 = 0.f;
    #pragma unroll
    for (int q = 0; q < 4; ++q)
        l2 += (r[q].x*r[q].x + r[q].y*r[q].y) + (r[q].z*r[q].z + r[q].w*r[q].w);
    const unsigned ab = __float_as_uint(a);
    const unsigned lb = __float_as_uint(l2);
    #pragma unroll
    for (int q = 0; q < 4; ++q) {
        uint4 o;
        o.x = pack2(r[q].x, r[q].y);
        o.y = pack2(r[q].z, r[q].w);
        o.z = ab; o.w = lb;
        dst[q] = o;
    }
}

// pool: grid 2048, block 256 = 16 samples x 16 lanes (4 l-phases x 4 chunks).
// f = bx & 3 interleaves fields in dispatch order. ids staged in LDS (R10).
// Movie/tag: ONE scattered 64B record line per element; lane c's 16B quarter
// is self-contained (v + att + l2), so the loop body has ZERO cross-lane ops:
// load -> unpack (2 shift / 2 and) -> FMA accumulate. Depth-1 pipeline.
// Genre: gtab/gexp/ids in LDS, no vmem in the loop.
// Stats: per-block float partials (no atomics); coef reduces in double.
// Padded tail (l >= ln): contributes 0 to s/ssq/att, exp(0)*(L-ln) added to
// the softmax denom analytically, never wins argmax (l2=0, strict >) or
// argmin (maps to 9999, first real l wins via strict <). First-index
// semantics preserved across phases by carrying l, tie -> smaller l.
__global__ __launch_bounds__(256) void pool_kernel(
    const int* __restrict__ ids_ug, const int* __restrict__ ids_urb,
    const int* __restrict__ ids_mg, const int* __restrict__ ids_mt,
    const int* __restrict__ len_ug, const int* __restrict__ len_urb,
    const int* __restrict__ len_mg, const int* __restrict__ len_mt,
    const uint4* __restrict__ pk_movie, const uint4* __restrict__ pk_tag,
    const float* __restrict__ emb_genre, const float* __restrict__ att_genre,
    float* __restrict__ pooled, float* __restrict__ psum, float* __restrict__ psq)
{
    const int bx  = blockIdx.x;
    const int f   = bx & 3;          // field, interleaved in dispatch order
    const int g   = bx >> 2;         // sample group (0..511)
    const int tid = threadIdx.x;
    const int sub = tid >> 4;        // sample within block (0..15)
    const int e   = tid & 15;        // lane within sample
    const int j   = e >> 2;          // l-phase
    const int c   = e & 3;           // chunk / record-quarter
    const int b   = g * 16 + sub;

    const int* ids; const int* lens; const uint4* pk;
    switch (f) {
        case 0: ids = ids_ug;  lens = len_ug;  pk = 0;         break;
        case 1: ids = ids_urb; lens = len_urb; pk = pk_movie;  break;
        case 2: ids = ids_mg;  lens = len_mg;  pk = 0;         break;
        default:ids = ids_mt;  lens = len_mt;  pk = pk_tag;    break;
    }
    const int ln = lens[b];

    __shared__ float tile[16][100];  // stats tile (stride 100, odd pad)
    __shared__ int   sids[16 * 100]; // block's id rows (coalesced staging)
    __shared__ float gtab[480];      // genre table (30 rows x 16)
    __shared__ float gexp[32];       // exp(att_genre)

    {   // coalesced int4 staging of all 16 id rows (1600 ints = 400 int4)
        const int4* idsrc = (const int4*)(ids + (size_t)g * (16 * L));
        ((int4*)sids)[tid] = idsrc[tid];
        if (tid < 144) ((int4*)sids)[256 + tid] = idsrc[256 + tid];
    }
    const bool genre = (f == 0) | (f == 2);
    if (genre) {                     // block-uniform branch
        for (int i = tid; i < 480; i += 256) gtab[i] = emb_genre[i];
        if (tid < 30) gexp[tid] = __expf(att_genre[tid]);
    }
    __syncthreads();
    const int* idrow = &sids[sub * 100];

    float4 s   = make_float4(0.f, 0.f, 0.f, 0.f);
    float4 ssq = s, att = s, mxv = s, mnv = s;
    float expsum = 0.f;
    float bestmx = -1e30f; int lx = 0x7fffffff;
    float bestmn =  1e30f; int lm = 0x7fffffff;

    // shared accumulate tail given v (this lane's 4 dims), per-row l2, exp(aw)
    auto ACCV = [&](const float4 v, const float l2v, const float ew, const int l) {
        s.x += v.x; s.y += v.y; s.z += v.z; s.w += v.w;
        ssq.x += v.x * v.x; ssq.y += v.y * v.y;
        ssq.z += v.z * v.z; ssq.w += v.w * v.w;
        if (l2v > bestmx) { bestmx = l2v; lx = l; mxv = v; }   // first-max
        float l2m = (l2v == 0.0f) ? 9999.0f : l2v;
        if (l2m < bestmn) { bestmn = l2m; lm = l; mnv = v; }   // first-min
        expsum += ew;
        att.x += v.x * ew; att.y += v.y * ew; att.z += v.z * ew; att.w += v.w * ew;
    };

    if (!genre) {
        // self-contained quarter -> (v, l2, aw); no cross-lane ops
        auto ACCP = [&](const uint4 q, const int l) {
            float4 v;
            v.x = __uint_as_float(q.x << 16);
            v.y = __uint_as_float(q.x & 0xffff0000u);
            v.z = __uint_as_float(q.y << 16);
            v.w = __uint_as_float(q.y & 0xffff0000u);
            ACCV(v, __uint_as_float(q.w), __expf(__uint_as_float(q.z)), l);
        };
        // depth-1 pipeline: next record line in flight during ACC
        int l = j;
        if (l < ln) {
            uint4 q0 = pk[(size_t)idrow[l] * 4 + c];
            while (l + 4 < ln) {
                uint4 q1 = pk[(size_t)idrow[l + 4] * 4 + c];
                ACCP(q0, l);
                q0 = q1; l += 4;
            }
            ACCP(q0, l);
        }
    } else {
        // fully LDS-resident loop; l2 via quad reduce (exact fp32)
        for (int l = j; l < ln; l += 4) {
            const int id = idrow[l];
            float4 v = *(const float4*)&gtab[id * 16 + c * 4];
            float pl2 = (v.x * v.x + v.y * v.y) + (v.z * v.z + v.w * v.w);
            float l2v = pl2 + __shfl_xor(pl2, 1);
            l2v += __shfl_xor(l2v, 2);
            ACCV(v, l2v, gexp[id], l);
        }
    }

    // cross-phase merges (masks 4, 8 flip j-bits; stay within 16-lane group)
    #pragma unroll
    for (int m = 4; m <= 8; m <<= 1) {
        float obx = __shfl_xor(bestmx, m);
        int   olx = __shfl_xor(lx, m);
        float ax = __shfl_xor(mxv.x, m), ay = __shfl_xor(mxv.y, m);
        float az = __shfl_xor(mxv.z, m), aw2 = __shfl_xor(mxv.w, m);
        if (obx > bestmx || (obx == bestmx && olx < lx)) {
            bestmx = obx; lx = olx; mxv = make_float4(ax, ay, az, aw2);
        }
        float obn = __shfl_xor(bestmn, m);
        int   olm = __shfl_xor(lm, m);
        float bx2 = __shfl_xor(mnv.x, m), by = __shfl_xor(mnv.y, m);
        float bz  = __shfl_xor(mnv.z, m), bw = __shfl_xor(mnv.w, m);
        if (obn < bestmn || (obn == bestmn && olm < lm)) {
            bestmn = obn; lm = olm; mnv = make_float4(bx2, by, bz, bw);
        }
        s.x += __shfl_xor(s.x, m); s.y += __shfl_xor(s.y, m);
        s.z += __shfl_xor(s.z, m); s.w += __shfl_xor(s.w, m);
        ssq.x += __shfl_xor(ssq.x, m); ssq.y += __shfl_xor(ssq.y, m);
        ssq.z += __shfl_xor(ssq.z, m); ssq.w += __shfl_xor(ssq.w, m);
        att.x += __shfl_xor(att.x, m); att.y += __shfl_xor(att.y, m);
        att.z += __shfl_xor(att.z, m); att.w += __shfl_xor(att.w, m);
        expsum += __shfl_xor(expsum, m);
    }
    expsum += (float)(L - ln);   // analytic padded-tail exp(0) contributions

    float4 mean;
    mean.x = s.x * (1.0f / L); mean.y = s.y * (1.0f / L);
    mean.z = s.z * (1.0f / L); mean.w = s.w * (1.0f / L);
    float4 ko;
    ko.x = 0.5f * (s.x * s.x - ssq.x); ko.y = 0.5f * (s.y * s.y - ssq.y);
    ko.z = 0.5f * (s.z * s.z - ssq.z); ko.w = 0.5f * (s.w * s.w - ssq.w);
    float pk2 = (ko.x * ko.x + ko.y * ko.y) + (ko.z * ko.z + ko.w * ko.w);
    float kn2 = pk2 + __shfl_xor(pk2, 1);
    kn2 += __shfl_xor(kn2, 2);
    float rn = 1.0f / fmaxf(sqrtf(kn2), 1e-12f);
    ko.x *= rn; ko.y *= rn; ko.z *= rn; ko.w *= rn;
    float ie = 1.0f / expsum;
    att.x *= ie; att.y *= ie; att.z *= ie; att.w *= ie;

    float4 pv[6] = { s, mean, mxv, mnv, ko, att };

    float4* prow = (float4*)(pooled + ((size_t)(f * BATCH + b)) * 96);
    if (j == 0) {                     // e < 4, c == e
        #pragma unroll
        for (int p = 0; p < 6; ++p) {
            prow[p * 4 + c] = pv[p];
            *(float4*)&tile[sub][p * 16 + c * 4] = pv[p];
        }
    }
    __syncthreads();
    // block-level partial stats -> plain stores (no atomics)
    if (tid < 96) {
        float sm = 0.f, sq = 0.f;
        #pragma unroll
        for (int s2 = 0; s2 < 16; ++s2) {
            float x = tile[s2][tid];
            sm += x;
            sq += x * x;
        }
        psum[(size_t)(f * 96 + tid) * NG + g] = sm;
        psq [(size_t)(f * 96 + tid) * NG + g] = sq;
    }
}

// coef: grid 12 x 256. Block covers 32 channels; 8 threads per channel
// reduce its 512 partials (coalesced float4 strips) in DOUBLE, then fold
// BN affine + softmax(alpha) weight into per-channel A,B.
__global__ __launch_bounds__(256) void coef_kernel(
    const float* __restrict__ psum, const float* __restrict__ psq,
    const float* __restrict__ gamma, const float* __restrict__ beta,
    const float* __restrict__ alpha,
    float* __restrict__ coefA, float* __restrict__ coefB)
{
    const int tid   = threadIdx.x;
    const int chl   = tid >> 3;              // local channel 0..31
    const int strip = tid & 7;               // 0..7
    const int ch    = blockIdx.x * 32 + chl; // 0..383
    const float4* ps = (const float4*)(psum + (size_t)ch * NG + strip * 64);
    const float4* pq = (const float4*)(psq  + (size_t)ch * NG + strip * 64);
    double dsm = 0.0, dsq = 0.0;
    #pragma unroll
    for (int i = 0; i < 16; ++i) {
        float4 a = ps[i];
        dsm += ((double)a.x + (double)a.y) + ((double)a.z + (double)a.w);
        float4 bq = pq[i];
        dsq += ((double)bq.x + (double)bq.y) + ((double)bq.z + (double)bq.w);
    }
    #pragma unroll
    for (int m = 1; m <= 4; m <<= 1) {
        dsm += __shfl_xor(dsm, m);
        dsq += __shfl_xor(dsq, m);
    }
    if (strip == 0) {
        const int f = ch / 96;
        const int p = (ch % 96) >> 4;
        double mu  = dsm * (1.0 / BATCH);
        double var = dsq * (1.0 / BATCH) - mu * mu;
        float inv = (float)(1.0 / sqrt(var + 1e-5));
        float gm = gamma[ch];
        float bb = beta[ch];
        float amax = -1e30f;
        for (int q = 0; q < 6; ++q) amax = fmaxf(amax, alpha[f * 6 + q]);
        float wsum = 0.f;
        for (int q = 0; q < 6; ++q) wsum += __expf(alpha[f * 6 + q] - amax);
        float wp = __expf(alpha[f * 6 + p] - amax) / wsum;
        coefA[ch] = wp * gm * inv;
        coefB[ch] = wp * (bb - gm * (float)mu * inv);
    }
}

#define SPB 16
__global__ __launch_bounds__(256) void final_kernel(
    const int* __restrict__ uid, const int* __restrict__ mid, const int* __restrict__ yr,
    const float* __restrict__ emb_user, const float* __restrict__ emb_movie,
    const float* __restrict__ emb_year,
    const float* __restrict__ pooled,
    const float* __restrict__ coefA, const float* __restrict__ coefB,
    const float* __restrict__ W1, const float* __restrict__ b1,
    const float* __restrict__ W2, const float* __restrict__ b2,
    const float* __restrict__ W3, const float* __restrict__ b3,
    float* __restrict__ out)
{
    __shared__ float sW1[112 * 64];   // [k][j], j contiguous
    __shared__ float sW2[64 * 32];
    __shared__ float sW3[32];
    __shared__ float sb1[64];
    __shared__ float sb2[32];
    __shared__ float xt[SPB][112];
    __shared__ float h1t[SPB][64];

    const int tid = threadIdx.x;
    for (int i = tid; i < 112 * 16; i += 256)
        ((float4*)sW1)[i] = ((const float4*)W1)[i];
    for (int i = tid; i < 64 * 8; i += 256)
        ((float4*)sW2)[i] = ((const float4*)W2)[i];
    if (tid < 32) sW3[tid] = W3[tid];
    if (tid < 64) sb1[tid] = b1[tid];
    if (tid < 32) sb2[tid] = b2[tid];

    const int sub = tid >> 4;
    const int e   = tid & 15;
    const int b   = blockIdx.x * SPB + sub;

    xt[sub][e]      = emb_user [(size_t)uid[b] * EMB + e];
    xt[sub][16 + e] = emb_movie[(size_t)mid[b] * EMB + e];
    xt[sub][32 + e] = emb_year [(size_t)yr[b]  * EMB + e];

    #pragma unroll
    for (int f = 0; f < 4; ++f) {
        const float* pr = pooled + ((size_t)(f * BATCH + b)) * 96;
        float acc = 0.f;
        #pragma unroll
        for (int p = 0; p < 6; ++p) {
            int c = f * 96 + p * 16 + e;
            acc += coefA[c] * pr[p * 16 + e] + coefB[c];
        }
        xt[sub][48 + f * 16 + e] = acc;
    }
    __syncthreads();

    // h1 = relu(x @ W1 + b1): lane e computes j = 4e..4e+3 via float4
    float4 h1 = ((float4*)sb1)[e];
    for (int k = 0; k < 112; ++k) {
        float xk = xt[sub][k];
        float4 w = ((float4*)sW1)[k * 16 + e];
        h1.x += xk * w.x; h1.y += xk * w.y; h1.z += xk * w.z; h1.w += xk * w.w;
    }
    float4 h1r;
    h1r.x = fmaxf(h1.x, 0.f); h1r.y = fmaxf(h1.y, 0.f);
    h1r.z = fmaxf(h1.z, 0.f); h1r.w = fmaxf(h1.w, 0.f);
    *(float4*)&h1t[sub][e * 4] = h1r;
    __syncthreads();

    // h2 = relu(h1 @ W2 + b2): lane e computes j = 2e, 2e+1 via float2
    float2 h2 = ((float2*)sb2)[e];
    for (int k = 0; k < 64; ++k) {
        float hk = h1t[sub][k];
        float2 w = ((float2*)sW2)[k * 16 + e];
        h2.x += hk * w.x; h2.y += hk * w.y;
    }
    float part = fmaxf(h2.x, 0.f) * sW3[2 * e] + fmaxf(h2.y, 0.f) * sW3[2 * e + 1];
    part += __shfl_xor(part, 1);
    part += __shfl_xor(part, 2);
    part += __shfl_xor(part, 4);
    part += __shfl_xor(part, 8);
    if (e == 0) {
        float t = part + b3[0];
        out[b] = 1.f / (1.f + __expf(-t));
    }
}

extern "C" void kernel_launch(void* const* d_in, const int* in_sizes, int n_in,
                              void* d_out, int out_size, void* d_ws, size_t ws_size,
                              hipStream_t stream) {
    const int* uid     = (const int*)d_in[0];
    const int* mid     = (const int*)d_in[1];
    const int* yr      = (const int*)d_in[2];
    const int* ids_ug  = (const int*)d_in[3];
    const int* ids_urb = (const int*)d_in[4];
    const int* ids_mg  = (const int*)d_in[5];
    const int* ids_mt  = (const int*)d_in[6];
    const int* len_ug  = (const int*)d_in[7];
    const int* len_urb = (const int*)d_in[8];
    const int* len_mg  = (const int*)d_in[9];
    const int* len_mt  = (const int*)d_in[10];
    const float* emb_user  = (const float*)d_in[11];
    const float* emb_movie = (const float*)d_in[12];
    const float* emb_tag   = (const float*)d_in[13];
    const float* emb_genre = (const float*)d_in[14];
    const float* emb_year  = (const float*)d_in[15];
    const float* att_movie = (const float*)d_in[16];
    const float* att_tag   = (const float*)d_in[17];
    const float* att_genre = (const float*)d_in[18];
    const float* bn_gamma  = (const float*)d_in[19];
    const float* bn_beta   = (const float*)d_in[20];
    const float* alpha     = (const float*)d_in[21];
    const float* W1 = (const float*)d_in[22];
    const float* b1 = (const float*)d_in[23];
    const float* W2 = (const float*)d_in[24];
    const float* b2 = (const float*)d_in[25];
    const float* W3 = (const float*)d_in[26];
    const float* b3 = (const float*)d_in[27];
    float* out = (float*)d_out;

    float* pooled = (float*)d_ws;
    float* psum   = pooled + POOLED_FLOATS;
    float* psq    = psum + PART_FLOATS;
    float* coefA  = psq + PART_FLOATS;
    float* coefB  = coefA + NCH;
    uint4* pk_movie = (uint4*)((char*)d_ws + (size_t)WS_HDR_FLOATS * 4);
    uint4* pk_tag   = pk_movie + (size_t)N_MOVIE * 4;

    pack_kernel<<<(N_MOVIE + N_TAG + 255) / 256, 256, 0, stream>>>(
        emb_movie, att_movie, emb_tag, att_tag, pk_movie, pk_tag);
    pool_kernel<<<4 * NG, 256, 0, stream>>>(
        ids_ug, ids_urb, ids_mg, ids_mt,
        len_ug, len_urb, len_mg, len_mt,
        pk_movie, pk_tag, emb_genre, att_genre,
        pooled, psum, psq);
    coef_kernel<<<12, 256, 0, stream>>>(psum, psq, bn_gamma, bn_beta, alpha,
                                        coefA, coefB);
    final_kernel<<<BATCH / SPB, 256, 0, stream>>>(
        uid, mid, yr, emb_user, emb_movie, emb_year,
        pooled, coefA, coefB, W1, b1, W2, b2, W3, b3, out);
}